// Round 13
// baseline (28.872 us; speedup 1.0000x reference)
//
#include <hip/hip_runtime.h>
#include <math.h>

#define DIM    128
#define DIM2   256
#define NSIGN  4
#define CCONST 0.618f
#define MB     16
#define NTHR   64

typedef short bf16x8 __attribute__((ext_vector_type(8)));
typedef float f32x4  __attribute__((ext_vector_type(4)));

#define MFMA(a,b,c) __builtin_amdgcn_mfma_f32_16x16x32_bf16((a),(b),(c),0,0,0)
#define LGKM0() asm volatile("s_waitcnt lgkmcnt(0)" ::: "memory")

union BU { uint4 q; bf16x8 b; unsigned short u[8]; };

__device__ __forceinline__ unsigned short f2bf(float f) {
    unsigned u = __float_as_uint(f);
    u += 0x7fffu + ((u >> 16) & 1u);          // round-to-nearest-even
    return (unsigned short)(u >> 16);
}
__device__ __forceinline__ float bf2f(unsigned short h) {
    return __uint_as_float(((unsigned)h) << 16);
}
__device__ __forceinline__ bf16x8 frag16(const unsigned short* p) {
    BU u; u.q = *(const uint4*)p; return u.b;
}

// ---------------- prep: pack 4 weight panels into MFMA fragment order (R10 wide) ----------------
// pack m: [nt][kt][lane][e] with value B[kt*32 + 8*(lane>>4) + e][nt*16 + (lane&15)]
//   m=0: W1T (hi+lo)  m=1: W2T (hi)  m=2: W2 (hi)  m=3: W1 (hi); pack stride 65536 ushort
__global__ void prep_pack(const float* __restrict__ W1, const float* __restrict__ W2,
                          unsigned short* __restrict__ pk) {
    int tid  = blockIdx.x * 256 + threadIdx.x;   // 65536 threads
    int lane = tid & 63;
    int rest = tid >> 6;                          // 0..1023
    int es   = rest & 3;                          // e-pair index
    int tkt  = (rest >> 2) & 63;                  // nt*KT + kt
    int m    = rest >> 8;                         // 0..3
    int r0   = ((tkt & ((m == 0 || m == 2) ? 3 : 7)) * 32) + ((lane >> 4) << 3) + es * 2;
    int nt   = tkt / ((m == 0 || m == 2) ? 4 : 8);
    int c    = nt * 16 + (lane & 15);

    unsigned short h[2], l[2];
    #pragma unroll
    for (int d = 0; d < 2; ++d) {
        int r = r0 + d;
        float v;
        if      (m == 0) v = W1[c * DIM  + r];
        else if (m == 1) v = W2[c * DIM2 + r];
        else if (m == 2) v = W2[r * DIM2 + c];
        else             v = W1[r * DIM  + c];
        unsigned short hb = f2bf(v);
        h[d] = hb;
        if (m == 0) l[d] = f2bf(v - bf2f(hb));
    }
    size_t base = (size_t)m * 65536 + (size_t)(tkt * 64 + lane) * 8 + es * 2;
    *(unsigned*)(pk + base) = (unsigned)h[0] | ((unsigned)h[1] << 16);
    if (m == 0)
        *(unsigned*)(pk + base + 32768) = (unsigned)l[0] | ((unsigned)l[1] << 16);
}

// -------- fused main: ONE WAVE per block, MB=16, ZERO barriers (same-wave LDS pipeline) --------
__global__ __launch_bounds__(NTHR, 1)
void fused_connection(const float* __restrict__ input_,
                      const float* __restrict__ b1,
                      const float* __restrict__ b2,
                      const unsigned short* __restrict__ pk,
                      float* __restrict__ out) {
    __shared__ __align__(16) float          vv [MB][132];
    __shared__ __align__(16) unsigned short xbH[MB][136];
    __shared__ __align__(16) unsigned short xbL[MB][136];
    __shared__ __align__(16) unsigned short vbH[MB][136];
    __shared__ __align__(16) unsigned short aH [MB][264];
    __shared__ __align__(16) unsigned short mwH[MB][264];   // mw ; overwritten by mu in pass 3
    __shared__ __align__(16) unsigned short vcH[MB][136];

    const int lane  = threadIdx.x;       // 0..63
    const int b0    = blockIdx.x * MB;
    const int arow  = lane & 15;         // A-frag row / B/C column component
    const int kg    = (lane >> 4) << 3;  // k-offset of lane group
    const int rbase = (lane >> 4) << 2;  // C/D row base (verified m89 layout)

    // ---- phase 0: load all 16 rows (1 row per iteration, fully coalesced) ----
    float4 fr[16];
    #pragma unroll
    for (int r = 0; r < 16; ++r)
        fr[r] = *(const float4*)(input_ + (size_t)(b0 + r) * DIM2 + lane * 4);

    if (lane < 32) {                     // x half: cols 0..127
        const int c = lane * 4;
        #pragma unroll
        for (int r = 0; r < 16; ++r) {
            float fa[4] = {fr[r].x, fr[r].y, fr[r].z, fr[r].w};
            union { unsigned short u[4]; ushort4 q; } H, L;
            #pragma unroll
            for (int e = 0; e < 4; ++e) {
                unsigned short hb = f2bf(fa[e]);
                H.u[e] = hb;
                L.u[e] = f2bf(fa[e] - bf2f(hb));
            }
            *(ushort4*)&xbH[r][c] = H.q;
            *(ushort4*)&xbL[r][c] = L.q;
        }
    } else {                             // v half: cols 128..255
        const int c = lane * 4 - DIM;
        #pragma unroll
        for (int r = 0; r < 16; ++r) {
            *(float4*)&vv[r][c] = fr[r];
            float fa[4] = {fr[r].x, fr[r].y, fr[r].z, fr[r].w};
            union { unsigned short u[4]; ushort4 q; } H;
            #pragma unroll
            for (int e = 0; e < 4; ++e) H.u[e] = f2bf(fa[e]);
            *(ushort4*)&vbH[r][c] = H.q;
            *(float4*)(out + (size_t)(b0 + r) * DIM2 + c) = fr[r];   // v -> out[:, :128]
        }
    }
    LGKM0();

    // ---- Pass 1: all 16 nt tiles (pairs for ILP): h = x.W1^T + b1 (3-term), w = v.W1^T ----
    {
        bf16x8 xH[4], xL[4], vH[4];
        #pragma unroll
        for (int kt = 0; kt < 4; ++kt) {
            const int k0 = kt * 32 + kg;
            xH[kt] = frag16(&xbH[arow][k0]);
            xL[kt] = frag16(&xbL[arow][k0]);
            vH[kt] = frag16(&vbH[arow][k0]);
        }
        #pragma unroll
        for (int np = 0; np < 8; ++np) {
            uint4 bh[2][4], bl[2][4];
            #pragma unroll
            for (int j = 0; j < 2; ++j)
                #pragma unroll
                for (int kt = 0; kt < 4; ++kt) {
                    const unsigned short* bp =
                        pk + (size_t)((((np * 2 + j) * 4 + kt) * 64 + lane) * 8);
                    bh[j][kt] = *(const uint4*)bp;
                    bl[j][kt] = *(const uint4*)(bp + 32768);
                }
            const float bv0 = b1[(np * 2 + 0) * 16 + arow];
            const float bv1 = b1[(np * 2 + 1) * 16 + arow];
            f32x4 ha0 = {0.f,0.f,0.f,0.f}, ha1 = {0.f,0.f,0.f,0.f};
            f32x4 wa0 = {0.f,0.f,0.f,0.f}, wa1 = {0.f,0.f,0.f,0.f};
            #pragma unroll
            for (int kt = 0; kt < 4; ++kt) {
                BU h0, l0, h1, l1;
                h0.q = bh[0][kt]; l0.q = bl[0][kt];
                h1.q = bh[1][kt]; l1.q = bl[1][kt];
                ha0 = MFMA(xH[kt], h0.b, ha0);
                ha1 = MFMA(xH[kt], h1.b, ha1);
                ha0 = MFMA(xH[kt], l0.b, ha0);
                ha1 = MFMA(xH[kt], l1.b, ha1);
                ha0 = MFMA(xL[kt], h0.b, ha0);
                ha1 = MFMA(xL[kt], h1.b, ha1);
                wa0 = MFMA(vH[kt], h0.b, wa0);
                wa1 = MFMA(vH[kt], h1.b, wa1);
            }
            #pragma unroll
            for (int j = 0; j < 2; ++j) {
                const int   col  = (np * 2 + j) * 16 + arow;
                const float bias = j ? bv1 : bv0;
                const f32x4 ha   = j ? ha1 : ha0;
                const f32x4 wa   = j ? wa1 : wa0;
                #pragma unroll
                for (int reg = 0; reg < 4; ++reg) {
                    const int row = rbase + reg;
                    float hv = ha[reg] + bias;
                    bool  mk = hv > 0.f;
                    aH[row][col]  = f2bf(mk ? hv : 0.f);
                    mwH[row][col] = f2bf(mk ? wa[reg] : 0.f);
                }
            }
        }
    }
    LGKM0();

    // ---- Pass 2: all 8 ci tiles (pairs): z = a.W2^T + b2 -> s; t2 = mw.W2^T ; write vc ----
    float sreg[8][4];
    f32x4 t2s[8];
    {
        bf16x8 af[8], mf[8];
        #pragma unroll
        for (int kt = 0; kt < 8; ++kt) {
            const int k0 = kt * 32 + kg;
            af[kt] = frag16(&aH[arow][k0]);
            mf[kt] = frag16(&mwH[arow][k0]);
        }
        #pragma unroll
        for (int cp = 0; cp < 4; ++cp) {
            uint4 bq[2][8];
            #pragma unroll
            for (int j = 0; j < 2; ++j)
                #pragma unroll
                for (int kt = 0; kt < 8; ++kt)
                    bq[j][kt] = *(const uint4*)(pk + 65536 +
                        (size_t)((((cp * 2 + j) * 8 + kt) * 64 + lane) * 8));
            const float b2v0 = b2[(cp * 2 + 0) * 16 + arow];
            const float b2v1 = b2[(cp * 2 + 1) * 16 + arow];
            f32x4 za0 = {0.f,0.f,0.f,0.f}, za1 = {0.f,0.f,0.f,0.f};
            f32x4 t20 = {0.f,0.f,0.f,0.f}, t21 = {0.f,0.f,0.f,0.f};
            #pragma unroll
            for (int kt = 0; kt < 8; ++kt) {
                BU q0, q1; q0.q = bq[0][kt]; q1.q = bq[1][kt];
                za0 = MFMA(af[kt], q0.b, za0);
                za1 = MFMA(af[kt], q1.b, za1);
                t20 = MFMA(mf[kt], q0.b, t20);
                t21 = MFMA(mf[kt], q1.b, t21);
            }
            #pragma unroll
            for (int j = 0; j < 2; ++j) {
                const int   ti = cp * 2 + j;
                const int   ci = ti * 16 + arow;
                const float sg = (ci < NSIGN) ? -1.f : 1.f;
                const float bb = j ? b2v1 : b2v0;
                const f32x4 za = j ? za1 : za0;
                t2s[ti] = j ? t21 : t20;
                #pragma unroll
                for (int reg = 0; reg < 4; ++reg) {
                    const int row = rbase + reg;
                    float z = za[reg] + bb;
                    float s = 1.f / (1.f + __expf(-z));
                    sreg[ti][reg] = s;
                    float vvl = vv[row][ci];
                    vcH[row][ci] = f2bf(vvl * vvl * sg * s * (1.f - s));
                }
            }
        }
    }
    LGKM0();

    // ---- Pass 3: all 16 nt tiles (pairs): u = vc.W2 ; mu = mask*u -> mwH ----
    {
        bf16x8 cH[4];
        #pragma unroll
        for (int kt = 0; kt < 4; ++kt)
            cH[kt] = frag16(&vcH[arow][kt * 32 + kg]);
        #pragma unroll
        for (int np = 0; np < 8; ++np) {
            uint4 bq[2][4];
            #pragma unroll
            for (int j = 0; j < 2; ++j)
                #pragma unroll
                for (int kt = 0; kt < 4; ++kt)
                    bq[j][kt] = *(const uint4*)(pk + 2 * 65536 +
                        (size_t)((((np * 2 + j) * 4 + kt) * 64 + lane) * 8));
            f32x4 ua0 = {0.f,0.f,0.f,0.f}, ua1 = {0.f,0.f,0.f,0.f};
            #pragma unroll
            for (int kt = 0; kt < 4; ++kt) {
                BU q0, q1; q0.q = bq[0][kt]; q1.q = bq[1][kt];
                ua0 = MFMA(cH[kt], q0.b, ua0);
                ua1 = MFMA(cH[kt], q1.b, ua1);
            }
            #pragma unroll
            for (int j = 0; j < 2; ++j) {
                const int   ck = (np * 2 + j) * 16 + arow;
                const f32x4 ua = j ? ua1 : ua0;
                #pragma unroll
                for (int reg = 0; reg < 4; ++reg) {
                    const int row = rbase + reg;
                    bool mk = aH[row][ck] != 0;
                    mwH[row][ck] = f2bf(mk ? ua[reg] : 0.f);
                }
            }
        }
    }
    LGKM0();

    // ---- Pass 4: all 8 cj tiles (pairs): t1 = mu.W1 ; epilogue dv ----
    {
        bf16x8 mu[8];
        #pragma unroll
        for (int kt = 0; kt < 8; ++kt)
            mu[kt] = frag16(&mwH[arow][kt * 32 + kg]);
        #pragma unroll
        for (int cp = 0; cp < 4; ++cp) {
            uint4 bq[2][8];
            #pragma unroll
            for (int j = 0; j < 2; ++j)
                #pragma unroll
                for (int kt = 0; kt < 8; ++kt)
                    bq[j][kt] = *(const uint4*)(pk + 3 * 65536 +
                        (size_t)((((cp * 2 + j) * 8 + kt) * 64 + lane) * 8));
            f32x4 t10 = {0.f,0.f,0.f,0.f}, t11 = {0.f,0.f,0.f,0.f};
            #pragma unroll
            for (int kt = 0; kt < 8; ++kt) {
                BU q0, q1; q0.q = bq[0][kt]; q1.q = bq[1][kt];
                t10 = MFMA(mu[kt], q0.b, t10);
                t11 = MFMA(mu[kt], q1.b, t11);
            }
            #pragma unroll
            for (int j = 0; j < 2; ++j) {
                const int   ti = cp * 2 + j;
                const int   cj = ti * 16 + arow;
                const float sg = (cj < NSIGN) ? -1.f : 1.f;
                const f32x4 t1 = j ? t11 : t10;
                #pragma unroll
                for (int reg = 0; reg < 4; ++reg) {
                    const int row = rbase + reg;
                    float s  = sreg[ti][reg];
                    float cv = sg * s * (1.f - s);
                    float gi = 1.f / (sg * (s + CCONST));
                    float vvl = vv[row][cj];
                    float dv = fmaf(-gi, t1[reg], 2.f * vvl * gi * cv * t2s[ti][reg]);
                    out[(size_t)(b0 + row) * DIM2 + DIM + cj] = dv;
                }
            }
        }
    }
}

extern "C" void kernel_launch(void* const* d_in, const int* in_sizes, int n_in,
                              void* d_out, int out_size, void* d_ws, size_t ws_size,
                              hipStream_t stream) {
    // inputs: t, input_, W1, b1, W2, b2
    const float* input_ = (const float*)d_in[1];
    const float* W1 = (const float*)d_in[2];
    const float* b1 = (const float*)d_in[3];
    const float* W2 = (const float*)d_in[4];
    const float* b2 = (const float*)d_in[5];
    float* out = (float*)d_out;
    unsigned short* pk = (unsigned short*)d_ws;   // 4 packs x 128 KB = 512 KB

    const int batch = in_sizes[1] / DIM2;

    prep_pack<<<256, 256, 0, stream>>>(W1, W2, pk);
    fused_connection<<<batch / MB, NTHR, 0, stream>>>(input_, b1, b2, pk, out);
}

// Round 14
// 17.051 us; speedup vs baseline: 1.6932x; 1.6932x over previous
//
#include <hip/hip_runtime.h>
#include <math.h>

#define DIM    128
#define DIM2   256
#define NSIGN  4
#define CCONST 0.618f
#define MB     16
#define NTHR   512

typedef short bf16x8 __attribute__((ext_vector_type(8)));
typedef float f32x4  __attribute__((ext_vector_type(4)));

#define MFMA(a,b,c) __builtin_amdgcn_mfma_f32_16x16x32_bf16((a),(b),(c),0,0,0)

union BU { uint4 q; bf16x8 b; };

__device__ __forceinline__ unsigned short f2bf(float f) {
    unsigned u = __float_as_uint(f);
    u += 0x7fffu + ((u >> 16) & 1u);          // round-to-nearest-even
    return (unsigned short)(u >> 16);
}
__device__ __forceinline__ float bf2f(unsigned short h) {
    return __uint_as_float(((unsigned)h) << 16);
}
__device__ __forceinline__ bf16x8 frag16(const unsigned short* p) {
    BU u; u.q = *(const uint4*)p; return u.b;
}

// ---------------- prep: pack 4 weight panels into MFMA fragment order ----------------
// pack m: [nt][kt][lane][e] with value B[kt*32 + 8*(lane>>4) + e][nt*16 + (lane&15)]
//   m=0: W1T (hi+lo)  m=1: W2T (hi)  m=2: W2 (hi)  m=3: W1 (hi); pack stride 65536 ushort
__global__ void prep_pack(const float* __restrict__ W1, const float* __restrict__ W2,
                          unsigned short* __restrict__ pk) {
    int tid  = blockIdx.x * 256 + threadIdx.x;   // 65536 threads
    int lane = tid & 63;
    int rest = tid >> 6;                          // 0..1023
    int es   = rest & 3;                          // e-pair index
    int tkt  = (rest >> 2) & 63;                  // nt*KT + kt
    int m    = rest >> 8;                         // 0..3
    int r0   = ((tkt & ((m == 0 || m == 2) ? 3 : 7)) * 32) + ((lane >> 4) << 3) + es * 2;
    int nt   = tkt / ((m == 0 || m == 2) ? 4 : 8);
    int c    = nt * 16 + (lane & 15);

    unsigned short h[2], l[2];
    #pragma unroll
    for (int d = 0; d < 2; ++d) {
        int r = r0 + d;
        float v;
        if      (m == 0) v = W1[c * DIM  + r];
        else if (m == 1) v = W2[c * DIM2 + r];
        else if (m == 2) v = W2[r * DIM2 + c];
        else             v = W1[r * DIM  + c];
        unsigned short hb = f2bf(v);
        h[d] = hb;
        if (m == 0) l[d] = f2bf(v - bf2f(hb));
    }
    size_t base = (size_t)m * 65536 + (size_t)(tkt * 64 + lane) * 8 + es * 2;
    *(unsigned*)(pk + base) = (unsigned)h[0] | ((unsigned)h[1] << 16);
    if (m == 0)
        *(unsigned*)(pk + base + 32768) = (unsigned)l[0] | ((unsigned)l[1] << 16);
}

// ------- fused main (R10 structure + split accumulator chains for shorter dep depth) -------
__global__ __launch_bounds__(NTHR, 1)
void fused_connection(const float* __restrict__ input_,
                      const float* __restrict__ b1,
                      const float* __restrict__ b2,
                      const unsigned short* __restrict__ pk,
                      float* __restrict__ out) {
    __shared__ __align__(16) float          vv [MB][132];   // v fp32
    __shared__ __align__(16) unsigned short xbH[MB][136];   // x hi plane
    __shared__ __align__(16) unsigned short xbL[MB][136];   // x lo plane
    __shared__ __align__(16) unsigned short vbH[MB][136];   // v hi plane
    __shared__ __align__(16) unsigned short aH [MB][264];   // a  bf16-hi
    __shared__ __align__(16) unsigned short mwH[MB][264];   // mw hi ; reused as mu hi
    __shared__ __align__(16) unsigned short vcH[MB][136];   // vc hi

    const int t    = threadIdx.x;
    const int lane = t & 63;
    const int w    = t >> 6;             // wave id 0..7
    const int b0   = blockIdx.x * MB;
    const int arow = lane & 15;          // A-frag row / C-frag col component
    const int kg   = (lane >> 4) << 3;   // k-offset of this lane group
    const int rbase = (lane >> 4) << 2;  // C/D row base (verified m89 layout)

    // ---- issue the HBM input load FIRST (longest latency) ----
    const int prow = t >> 5;             // 0..15
    const int pc   = (t & 31) * 8;       // 0..248
    const float4* src = (const float4*)(input_ + (size_t)(b0 + prow) * DIM2 + pc);
    const float4 f0 = src[0];
    const float4 f1 = src[1];

    // ---- prefetch pass-1 B fragments (L2) + biases under the input-load shadow ----
    uint4 b1hq[2][4], b1lq[2][4];
    #pragma unroll
    for (int nt2 = 0; nt2 < 2; ++nt2)
        #pragma unroll
        for (int kt = 0; kt < 4; ++kt) {
            const unsigned short* bp = pk + (size_t)((((w * 2 + nt2) * 4 + kt) * 64 + lane) * 8);
            b1hq[nt2][kt] = *(const uint4*)bp;
            b1lq[nt2][kt] = *(const uint4*)(bp + 32768);
        }
    const float b1v0 = b1[(w * 2 + 0) * 16 + arow];
    const float b1v1 = b1[(w * 2 + 1) * 16 + arow];
    const float b2v  = b2[w * 16 + arow];

    // ---- phase 0: convert in-register, stage planes; v -> out ----
    {
        float fa[8] = {f0.x, f0.y, f0.z, f0.w, f1.x, f1.y, f1.z, f1.w};
        if (pc < DIM) {
            union { unsigned short u[8]; uint4 q; } H, L;
            #pragma unroll
            for (int e = 0; e < 8; ++e) {
                unsigned short hb = f2bf(fa[e]);
                H.u[e] = hb;
                L.u[e] = f2bf(fa[e] - bf2f(hb));
            }
            *(uint4*)&xbH[prow][pc] = H.q;
            *(uint4*)&xbL[prow][pc] = L.q;
        } else {
            int c = pc - DIM;
            *(float4*)&vv[prow][c]     = f0;
            *(float4*)&vv[prow][c + 4] = f1;
            union { unsigned short u[8]; uint4 q; } H;
            #pragma unroll
            for (int e = 0; e < 8; ++e) H.u[e] = f2bf(fa[e]);
            *(uint4*)&vbH[prow][c] = H.q;
            // v -> out[:, :128] straight from registers
            float4* op = (float4*)(out + (size_t)(b0 + prow) * DIM2 + c);
            op[0] = f0; op[1] = f1;
        }
    }
    __syncthreads();

    // ---- Pass 1: B=W1T -> h = x.W1^T + b1 (3-term split), w = v.W1^T (hi) ----
    // split accumulators: kt{0,1} -> chain A, kt{2,3} -> chain B (dep depth 12 -> 6)
    uint4 b2q[8];
    {
        const unsigned short* p1 = pk + 65536;
        #pragma unroll
        for (int kt = 0; kt < 8; ++kt)
            b2q[kt] = *(const uint4*)(p1 + (size_t)((w * 8 + kt) * 64 + lane) * 8);

        bf16x8 xH[4], xL[4], vH[4];
        #pragma unroll
        for (int kt = 0; kt < 4; ++kt) {
            int k0 = kt * 32 + kg;
            xH[kt] = frag16(&xbH[arow][k0]);
            xL[kt] = frag16(&xbL[arow][k0]);
            vH[kt] = frag16(&vbH[arow][k0]);
        }
        #pragma unroll
        for (int nt2 = 0; nt2 < 2; ++nt2) {
            f32x4 haA = {0.f,0.f,0.f,0.f}, haB = {0.f,0.f,0.f,0.f};
            f32x4 waA = {0.f,0.f,0.f,0.f}, waB = {0.f,0.f,0.f,0.f};
            #pragma unroll
            for (int kt = 0; kt < 2; ++kt) {
                BU bh, bl;
                bh.q = b1hq[nt2][kt];     bl.q = b1lq[nt2][kt];
                haA = MFMA(xH[kt], bh.b, haA);
                haA = MFMA(xH[kt], bl.b, haA);
                haA = MFMA(xL[kt], bh.b, haA);
                waA = MFMA(vH[kt], bh.b, waA);
                BU ch, cl;
                ch.q = b1hq[nt2][kt + 2]; cl.q = b1lq[nt2][kt + 2];
                haB = MFMA(xH[kt + 2], ch.b, haB);
                haB = MFMA(xH[kt + 2], cl.b, haB);
                haB = MFMA(xL[kt + 2], ch.b, haB);
                waB = MFMA(vH[kt + 2], ch.b, waB);
            }
            f32x4 ha = haA + haB;
            f32x4 wa = waA + waB;
            int col  = (w * 2 + nt2) * 16 + arow;
            float bias = nt2 ? b1v1 : b1v0;
            #pragma unroll
            for (int reg = 0; reg < 4; ++reg) {
                int row = rbase + reg;
                float hv = ha[reg] + bias;
                bool  mk = hv > 0.f;
                aH[row][col]  = f2bf(mk ? hv : 0.f);
                mwH[row][col] = f2bf(mk ? wa[reg] : 0.f);
            }
        }
    }
    __syncthreads();

    // ---- Pass 2: B=W2T(hi) -> z = a.W2^T + b2 (-> s), t2 = mw.W2^T ; write vc ----
    // split: kt{0..3} chain A, kt{4..7} chain B (dep depth 8 -> 4)
    float sreg[4];
    f32x4 t2a;
    uint4 b3q[2][4];
    {
        const unsigned short* p2 = pk + 2 * 65536;
        #pragma unroll
        for (int nt2 = 0; nt2 < 2; ++nt2)
            #pragma unroll
            for (int kt = 0; kt < 4; ++kt)
                b3q[nt2][kt] = *(const uint4*)(p2 + (size_t)((((w * 2 + nt2) * 4 + kt) * 64 + lane) * 8));

        f32x4 zaA = {0.f,0.f,0.f,0.f}, zaB = {0.f,0.f,0.f,0.f};
        f32x4 t2A = {0.f,0.f,0.f,0.f}, t2B = {0.f,0.f,0.f,0.f};
        #pragma unroll
        for (int kt = 0; kt < 4; ++kt) {
            {
                int k0 = kt * 32 + kg;
                bf16x8 af = frag16(&aH[arow][k0]);
                bf16x8 mf = frag16(&mwH[arow][k0]);
                BU bh; bh.q = b2q[kt];
                zaA = MFMA(af, bh.b, zaA);
                t2A = MFMA(mf, bh.b, t2A);
            }
            {
                int k0 = (kt + 4) * 32 + kg;
                bf16x8 af = frag16(&aH[arow][k0]);
                bf16x8 mf = frag16(&mwH[arow][k0]);
                BU bh; bh.q = b2q[kt + 4];
                zaB = MFMA(af, bh.b, zaB);
                t2B = MFMA(mf, bh.b, t2B);
            }
        }
        f32x4 za = zaA + zaB;
        t2a = t2A + t2B;
        int   ci   = w * 16 + arow;            // i in [0,128)
        float sg_i = (ci < NSIGN) ? -1.f : 1.f;
        #pragma unroll
        for (int reg = 0; reg < 4; ++reg) {
            int row = rbase + reg;
            float z = za[reg] + b2v;
            float s = 1.f / (1.f + __expf(-z));
            sreg[reg] = s;
            float vvl = vv[row][ci];
            vcH[row][ci] = f2bf(vvl * vvl * sg_i * s * (1.f - s));
        }
    }
    __syncthreads();

    // ---- Pass 3: B=W2(hi) -> u = vc.W2 ; write mu = mask*u into mwH ----
    // split: kt{0,1} chain A, kt{2,3} chain B (dep depth 4 -> 2)
    uint4 b4q[8];
    {
        const unsigned short* p3 = pk + 3 * 65536;
        #pragma unroll
        for (int kt = 0; kt < 8; ++kt)
            b4q[kt] = *(const uint4*)(p3 + (size_t)((w * 8 + kt) * 64 + lane) * 8);

        bf16x8 cH[4];
        #pragma unroll
        for (int kt = 0; kt < 4; ++kt)
            cH[kt] = frag16(&vcH[arow][kt * 32 + kg]);
        #pragma unroll
        for (int nt2 = 0; nt2 < 2; ++nt2) {
            f32x4 uaA = {0.f,0.f,0.f,0.f}, uaB = {0.f,0.f,0.f,0.f};
            #pragma unroll
            for (int kt = 0; kt < 2; ++kt) {
                BU bh; bh.q = b3q[nt2][kt];
                uaA = MFMA(cH[kt], bh.b, uaA);
                BU ch; ch.q = b3q[nt2][kt + 2];
                uaB = MFMA(cH[kt + 2], ch.b, uaB);
            }
            f32x4 ua = uaA + uaB;
            int ck = (w * 2 + nt2) * 16 + arow;   // k in [0,256)
            #pragma unroll
            for (int reg = 0; reg < 4; ++reg) {
                int row = rbase + reg;
                bool mk = aH[row][ck] != 0;       // a>0 <=> stored bf16 nonzero
                mwH[row][ck] = f2bf(mk ? ua[reg] : 0.f);
            }
        }
    }
    __syncthreads();

    // ---- Pass 4: B=W1(hi) -> t1 = mu.W1 ; epilogue dv ----
    // split: kt{0..3} chain A, kt{4..7} chain B (dep depth 8 -> 4)
    {
        f32x4 t1A = {0.f,0.f,0.f,0.f}, t1B = {0.f,0.f,0.f,0.f};
        #pragma unroll
        for (int kt = 0; kt < 4; ++kt) {
            {
                bf16x8 mf = frag16(&mwH[arow][kt * 32 + kg]);
                BU bh; bh.q = b4q[kt];
                t1A = MFMA(mf, bh.b, t1A);
            }
            {
                bf16x8 mf = frag16(&mwH[arow][(kt + 4) * 32 + kg]);
                BU bh; bh.q = b4q[kt + 4];
                t1B = MFMA(mf, bh.b, t1B);
            }
        }
        f32x4 t1a = t1A + t1B;
        int   cj   = w * 16 + arow;            // same col as pass 2 -> sreg/t2a align
        float sg_j = (cj < NSIGN) ? -1.f : 1.f;
        #pragma unroll
        for (int reg = 0; reg < 4; ++reg) {
            int row = rbase + reg;
            float s  = sreg[reg];
            float cv = sg_j * s * (1.f - s);
            float gi = 1.f / (sg_j * (s + CCONST));
            float vvl = vv[row][cj];
            float dv = fmaf(-gi, t1a[reg], 2.f * vvl * gi * cv * t2a[reg]);
            out[(size_t)(b0 + row) * DIM2 + DIM + cj] = dv;
        }
    }
}

extern "C" void kernel_launch(void* const* d_in, const int* in_sizes, int n_in,
                              void* d_out, int out_size, void* d_ws, size_t ws_size,
                              hipStream_t stream) {
    // inputs: t, input_, W1, b1, W2, b2
    const float* input_ = (const float*)d_in[1];
    const float* W1 = (const float*)d_in[2];
    const float* b1 = (const float*)d_in[3];
    const float* W2 = (const float*)d_in[4];
    const float* b2 = (const float*)d_in[5];
    float* out = (float*)d_out;
    unsigned short* pk = (unsigned short*)d_ws;   // 4 packs x 128 KB = 512 KB

    const int batch = in_sizes[1] / DIM2;

    prep_pack<<<256, 256, 0, stream>>>(W1, W2, pk);
    fused_connection<<<batch / MB, NTHR, 0, stream>>>(input_, b1, b2, pk, out);
}